// Round 16
// baseline (259.958 us; speedup 1.0000x reference)
//
#include <hip/hip_runtime.h>
#include <math.h>

#define Bq 16
#define Sq 1024
#define Dq 128
#define Hq 8
#define DHq 16
#define DFFq 512
#define Lq 3
#define NCLS 6
#define NROWS (Bq * Sq)       // 16384
#define NX ((size_t)NROWS * Dq)   // 2,097,152 floats

// Q pre-scale: (1/sqrt(DH)) * log2(e), so softmax probs = 2^score (raw v_exp)
#define QSCL 0.36067376022224085f

typedef __attribute__((ext_vector_type(8))) short    bf16x8;
typedef __attribute__((ext_vector_type(4))) float    f32x4;
typedef __attribute__((ext_vector_type(4))) _Float16 f16x4;
typedef __attribute__((ext_vector_type(8))) _Float16 f16x8;

__device__ inline ushort f32_to_bf16(float f) {
    union { float f; unsigned u; } v; v.f = f;
    unsigned r = v.u + 0x7fffu + ((v.u >> 16) & 1u);
    return (ushort)(r >> 16);
}

// raw 2^x via v_exp_f32 (ISA-guaranteed); avoids __expf's extra v_mul
__device__ __forceinline__ float exp2_raw(float x) {
    float r;
    asm("v_exp_f32 %0, %1" : "=v"(r) : "v"(x));
    return r;
}

// ---------------------------------------------------------------------------
// prep: cast+transpose weights to bf16 Wt[n][k]; cast x to bf16.
// Wq PRE-SCALED by QSCL (ReLU commutes with positive scale).
// ---------------------------------------------------------------------------
__global__ __launch_bounds__(256) void prep_kernel(
    const float* __restrict__ Wqp, const float* __restrict__ Wkp,
    const float* __restrict__ Wvp, const float* __restrict__ W1p,
    const float* __restrict__ W2p, const float* __restrict__ xp,
    ushort* __restrict__ wbf, ushort* __restrict__ xbf)
{
    const int gid = blockIdx.x * 256 + threadIdx.x;
    if (gid < 147456) {                       // QKV transpose
        const int w   = gid / 49152;
        const int rem = gid - w * 49152;
        const int l   = rem >> 14;
        const int idx = rem & 16383;
        const int k   = idx >> 7;
        const int n   = idx & 127;
        const float* src = (w == 0) ? Wqp : (w == 1) ? Wkp : Wvp;
        const float scl = (w == 0) ? QSCL : 1.0f;
        wbf[(size_t)(w * 3 + l) * 16384 + n * 128 + k] =
            f32_to_bf16(src[(size_t)l * 16384 + k * 128 + n] * scl);
    } else if (gid < 344064) {                // W1 [128][512]->[512][128]
        const int g   = gid - 147456;
        const int l   = g >> 16;
        const int idx = g & 65535;
        const int k   = idx >> 9;
        const int n   = idx & 511;
        wbf[147456 + (size_t)l * 65536 + n * 128 + k] =
            f32_to_bf16(W1p[(size_t)l * 65536 + k * 512 + n]);
    } else if (gid < 540672) {                // W2 [512][128]->[128][512]
        const int g   = gid - 344064;
        const int l   = g >> 16;
        const int idx = g & 65535;
        const int k   = idx >> 7;
        const int n   = idx & 127;
        wbf[344064 + (size_t)l * 65536 + n * 512 + k] =
            f32_to_bf16(W2p[(size_t)l * 65536 + k * 128 + n]);
    } else {                                  // x cast
        const int g = gid - 540672;
        xbf[g] = f32_to_bf16(xp[g]);
    }
}

// ---------------------------------------------------------------------------
// Standalone QKV GEMM (layer 0 only; R12-proven). grid (256, 3).
// ---------------------------------------------------------------------------
__global__ __launch_bounds__(256) void gemm_qkv(
    const ushort* __restrict__ A,
    const ushort* __restrict__ wq, const ushort* __restrict__ wk,
    const ushort* __restrict__ wv,
    const float* __restrict__ bqp, const float* __restrict__ bkp,
    const float* __restrict__ bvp,
    _Float16* __restrict__ qo, _Float16* __restrict__ ko,
    _Float16* __restrict__ vo)
{
    __shared__ ushort As[64 * 40];
    __shared__ ushort Bs[128 * 40];

    const int sel  = blockIdx.y;
    const ushort* Bt   = (sel == 0) ? wq : (sel == 1) ? wk : wv;
    const float*  bias = (sel == 0) ? bqp : (sel == 1) ? bkp : bvp;
    const float   bscl = (sel == 0) ? QSCL : 1.0f;

    const int tid  = threadIdx.x;
    const int row0 = blockIdx.x * 64;
    const int wave = tid >> 6;
    const int lane = tid & 63;
    const int quad = lane >> 4;
    const int m16  = lane & 15;
    const int wm   = wave >> 1;
    const int wn   = wave & 1;

    const int sar = tid >> 2;
    const int sac = (tid & 3) * 8;

    f32x4 acc[2][4];
    #pragma unroll
    for (int i = 0; i < 2; ++i)
        #pragma unroll
        for (int j = 0; j < 4; ++j) acc[i][j] = (f32x4)0.f;

    for (int k0 = 0; k0 < 128; k0 += 32) {
        bf16x8 av = *(const bf16x8*)(A + (size_t)(row0 + sar) * 128 + k0 + sac);
        const int r1 = tid >> 2, r2 = r1 + 64;
        bf16x8 bv1 = *(const bf16x8*)(Bt + (size_t)r1 * 128 + k0 + sac);
        bf16x8 bv2 = *(const bf16x8*)(Bt + (size_t)r2 * 128 + k0 + sac);

        __syncthreads();
        *(bf16x8*)&As[sar * 40 + sac] = av;
        *(bf16x8*)&Bs[r1 * 40 + sac]  = bv1;
        *(bf16x8*)&Bs[r2 * 40 + sac]  = bv2;
        __syncthreads();

        bf16x8 af[2], bf[4];
        #pragma unroll
        for (int i = 0; i < 2; ++i)
            af[i] = *(const bf16x8*)&As[(32 * wm + 16 * i + m16) * 40 + quad * 8];
        #pragma unroll
        for (int j = 0; j < 4; ++j)
            bf[j] = *(const bf16x8*)&Bs[(64 * wn + 16 * j + m16) * 40 + quad * 8];
        #pragma unroll
        for (int i = 0; i < 2; ++i)
            #pragma unroll
            for (int j = 0; j < 4; ++j)
                acc[i][j] = __builtin_amdgcn_mfma_f32_16x16x32_bf16(af[i], bf[j], acc[i][j], 0, 0, 0);
    }

    #pragma unroll
    for (int i = 0; i < 2; ++i) {
        #pragma unroll
        for (int j = 0; j < 4; ++j) {
            const int col = 64 * wn + 16 * j + m16;
            const float bb = bias[col] * bscl;
            const int hh = col >> 4, dh = col & 15;
            #pragma unroll
            for (int r = 0; r < 4; ++r) {
                float val = fmaxf(acc[i][j][r] + bb, 0.f);
                const int gr = row0 + 32 * wm + 16 * i + quad * 4 + r;
                const int b = gr >> 10, s = gr & 1023;
                if (sel == 2) {
                    vo[(((size_t)b * Hq + hh) * DHq + dh) * Sq + s] = (_Float16)val;
                } else {
                    _Float16* outp = (sel == 0) ? qo : ko;
                    outp[(((size_t)b * Hq + hh) * Sq + s) * DHq + dh] = (_Float16)val;
                }
            }
        }
    }
}

// ---------------------------------------------------------------------------
// FUSED FFN BLOCK v3 — occupancy-focused (35.3 KB LDS -> 4 blocks/CU):
//  - DFF processed in two 256-col halves; Hs halved (32x264), FFN2 acc2
//    accumulates across halves.
//  - LN1 residual handoff via transient overlay on Bs -> registers (rreg);
//    vals LDS buffer eliminated.
//  - Bs 128x40, 32-K staging (R12-proven). Phase-D exchange & last-layer
//    projection overlay dead Hs; wo_s overlays dead Bs.
//  + next-layer QKV epilogue (R14-proven). o arrives f16.
// ---------------------------------------------------------------------------
__global__ __launch_bounds__(256, 4) void gemm_ffn_fused(
    const _Float16* __restrict__ o, const float* __restrict__ resid,
    const float* __restrict__ g1, const float* __restrict__ beta1,
    const ushort* __restrict__ W1t, const float* __restrict__ bias1,
    const ushort* __restrict__ W2t, const float* __restrict__ bias2,
    const float* __restrict__ g2, const float* __restrict__ beta2,
    float* __restrict__ xb,
    const ushort* __restrict__ wqn, const ushort* __restrict__ wkn,
    const ushort* __restrict__ wvn,
    const float* __restrict__ bqn, const float* __restrict__ bkn,
    const float* __restrict__ bvn,
    _Float16* __restrict__ qo, _Float16* __restrict__ ko,
    _Float16* __restrict__ vo, int do_next,
    const float* __restrict__ Wout, const float* __restrict__ bout,
    float* __restrict__ out, int last)
{
    __shared__ __align__(16) char smem[36096];
    ushort*    Af    = (ushort*)smem;                 // [0, 8704): 32x136 bf16
    ushort*    Hs    = (ushort*)(smem + 8704);        // [8704, 25600): 32x264 bf16
    ushort*    Bs    = (ushort*)(smem + 25600);       // [25600, 35840): 128x40
    _Float16*  r16   = (_Float16*)(smem + 25600);     // 32x132 f16, Phase A->B handoff (on Bs)
    _Float16*  vals2 = (_Float16*)(smem + 8704);      // 32x132 f16, Phase D exchange (on Hs)
    float*     wo_s  = (float*)(smem + 25600);        // last: 768 f32 (on Bs)
    float*     mus   = (float*)(smem + 35840);        // 32 f32
    float*     rsds  = (float*)(smem + 35968);        // 32 f32

    const int tid  = threadIdx.x;
    const int row0 = blockIdx.x * 32;
    const int wave = tid >> 6;
    const int lane = tid & 63;
    const int quad = lane >> 4;
    const int m16  = lane & 15;
    const int wm   = wave >> 1;          // row half: 16*wm
    const int wn   = wave & 1;           // col half: 64*wn
    const int sac  = (tid & 3) * 8;
    const int r1   = tid >> 2, r2 = r1 + 64;

    // ---- Phase A: LN1, 8 rows/wave, each row once ----
    #pragma unroll 2
    for (int it = 0; it < 8; ++it) {
        const int rr = wave * 8 + it;
        const size_t base = (size_t)(row0 + rr) * Dq;
        float v0 = (float)o[base + lane]      + resid[base + lane];
        float v1 = (float)o[base + 64 + lane] + resid[base + 64 + lane];

        float s = v0 + v1;
        #pragma unroll
        for (int off = 32; off > 0; off >>= 1) s += __shfl_xor(s, off, 64);
        const float mu = s * (1.f / 128.f);
        const float d0 = v0 - mu, d1 = v1 - mu;
        float vs = d0 * d0 + d1 * d1;
        #pragma unroll
        for (int off = 32; off > 0; off >>= 1) vs += __shfl_xor(vs, off, 64);
        const float rstd = rsqrtf(vs * (1.f / 128.f) + 1e-8f);

        const float rv0 = g1[lane]      * d0 * rstd + beta1[lane];
        const float rv1 = g1[lane + 64] * d1 * rstd + beta1[lane + 64];
        Af[rr * 136 + lane]       = f32_to_bf16(rv0);
        Af[rr * 136 + 64 + lane]  = f32_to_bf16(rv1);
        r16[rr * 132 + lane]      = (_Float16)rv0;
        r16[rr * 132 + 64 + lane] = (_Float16)rv1;
    }
    __syncthreads();

    // LN1 residual -> registers in Phase-D layout (r16 dies; Bs free)
    float rreg[4][4];
    #pragma unroll
    for (int j = 0; j < 4; ++j) {
        const int col = 64 * wn + 16 * j + m16;
        #pragma unroll
        for (int r = 0; r < 4; ++r)
            rreg[j][r] = (float)r16[(16 * wm + quad * 4 + r) * 132 + col];
    }

    // ---- Phases B+C, two DFF halves; acc2 accumulates across halves ----
    f32x4 acc2[4];
    #pragma unroll
    for (int j = 0; j < 4; ++j) acc2[j] = (f32x4)0.f;

    for (int half = 0; half < 2; ++half) {
        // FFN1 for output cols [half*256, half*256+256) -> Hs (local cols)
        f32x4 acc[4];
        #pragma unroll
        for (int j = 0; j < 4; ++j) acc[j] = (f32x4)0.f;

        for (int idx = 0; idx < 8; ++idx) {
            const int cc = idx >> 2;              // local col chunk 0/1
            const int k0 = (idx & 3) * 32;
            const int gc0 = half * 256 + cc * 128;

            bf16x8 wv1 = *(const bf16x8*)(W1t + (size_t)(gc0 + r1) * 128 + k0 + sac);
            bf16x8 wv2 = *(const bf16x8*)(W1t + (size_t)(gc0 + r2) * 128 + k0 + sac);

            __syncthreads();   // first iter also guards rreg reads above
            *(bf16x8*)&Bs[r1 * 40 + sac] = wv1;
            *(bf16x8*)&Bs[r2 * 40 + sac] = wv2;
            __syncthreads();

            const bf16x8 af = *(const bf16x8*)&Af[(16 * wm + m16) * 136 + k0 + quad * 8];
            bf16x8 bf[4];
            #pragma unroll
            for (int j = 0; j < 4; ++j)
                bf[j] = *(const bf16x8*)&Bs[(64 * wn + 16 * j + m16) * 40 + quad * 8];
            #pragma unroll
            for (int j = 0; j < 4; ++j)
                acc[j] = __builtin_amdgcn_mfma_f32_16x16x32_bf16(af, bf[j], acc[j], 0, 0, 0);

            if ((idx & 3) == 3) {   // end of 128-col chunk: epilogue + reset
                #pragma unroll
                for (int j = 0; j < 4; ++j) {
                    const int lcol = cc * 128 + 64 * wn + 16 * j + m16;
                    const float bb = bias1[half * 256 + lcol];
                    #pragma unroll
                    for (int r = 0; r < 4; ++r) {
                        const int row = 16 * wm + quad * 4 + r;
                        Hs[row * 264 + lcol] = f32_to_bf16(fmaxf(acc[j][r] + bb, 0.f));
                    }
                    acc[j] = (f32x4)0.f;
                }
            }
        }

        // FFN2 partial: k in [half*256, half*256+256) from resident Hs
        for (int kc = 0; kc < 8; ++kc) {
            const int k0 = kc * 32;   // local k

            bf16x8 wv1 = *(const bf16x8*)(W2t + (size_t)r1 * DFFq + half * 256 + k0 + sac);
            bf16x8 wv2 = *(const bf16x8*)(W2t + (size_t)r2 * DFFq + half * 256 + k0 + sac);

            __syncthreads();   // kc==0: guards this half's Hs writes
            *(bf16x8*)&Bs[r1 * 40 + sac] = wv1;
            *(bf16x8*)&Bs[r2 * 40 + sac] = wv2;
            __syncthreads();

            const bf16x8 af = *(const bf16x8*)&Hs[(16 * wm + m16) * 264 + k0 + quad * 8];
            bf16x8 bf[4];
            #pragma unroll
            for (int j = 0; j < 4; ++j)
                bf[j] = *(const bf16x8*)&Bs[(64 * wn + 16 * j + m16) * 40 + quad * 8];
            #pragma unroll
            for (int j = 0; j < 4; ++j)
                acc2[j] = __builtin_amdgcn_mfma_f32_16x16x32_bf16(af, bf[j], acc2[j], 0, 0, 0);
        }
    }

    // ---- Phase D: +bias2 +LN1-residual (regs), LN2 ----
    __syncthreads();   // all Hs/Bs reads done; vals2 (on Hs) and wo_s (on Bs) safe

    float vreg[4][4];
    #pragma unroll
    for (int j = 0; j < 4; ++j) {
        const int col = 64 * wn + 16 * j + m16;
        const float bb = bias2[col];
        #pragma unroll
        for (int r = 0; r < 4; ++r) {
            const int row = 16 * wm + quad * 4 + r;
            float v = acc2[j][r] + bb + rreg[j][r];
            vreg[j][r] = v;
            vals2[row * 132 + col] = (_Float16)v;
        }
    }
    if (last) {
        #pragma unroll
        for (int i = 0; i < 3; ++i) wo_s[tid + i * 256] = Wout[tid + i * 256];
    }
    __syncthreads();

    if (tid < 32) {
        float s = 0.f, s2 = 0.f;
        #pragma unroll 8
        for (int c = 0; c < Dq; ++c) {
            float x = (float)vals2[tid * 132 + c];
            s += x; s2 = fmaf(x, x, s2);
        }
        const float mu  = s * (1.f / 128.f);
        const float var = s2 * (1.f / 128.f) - mu * mu;
        mus[tid]  = mu;
        rsds[tid] = rsqrtf(var + 1e-6f);
    }
    __syncthreads();

    if (!last) {
        // LN2 output: xb f32 (next-layer residual) + Af bf16 (A-operand for
        // the fused next-layer QKV below).
        #pragma unroll
        for (int j = 0; j < 4; ++j) {
            const int col = 64 * wn + 16 * j + m16;
            #pragma unroll
            for (int r = 0; r < 4; ++r) {
                const int row = 16 * wm + quad * 4 + r;
                const float rn = g2[col] * (vreg[j][r] - mus[row]) * rsds[row] + beta2[col];
                xb[(size_t)(row0 + row) * Dq + col] = rn;
                Af[row * 136 + col] = f32_to_bf16(rn);
            }
        }

        if (do_next) {
            // ---- next-layer QKV from resident Af (32 rows), 32-K staging ----
            for (int sel = 0; sel < 3; ++sel) {
                const ushort* Bt   = (sel == 0) ? wqn : (sel == 1) ? wkn : wvn;
                const float*  bias = (sel == 0) ? bqn : (sel == 1) ? bkn : bvn;
                const float   bscl = (sel == 0) ? QSCL : 1.0f;

                f32x4 qacc[4];
                #pragma unroll
                for (int j = 0; j < 4; ++j) qacc[j] = (f32x4)0.f;

                for (int kc = 0; kc < 4; ++kc) {
                    const int k0 = kc * 32;
                    bf16x8 wv1 = *(const bf16x8*)(Bt + (size_t)r1 * 128 + k0 + sac);
                    bf16x8 wv2 = *(const bf16x8*)(Bt + (size_t)r2 * 128 + k0 + sac);

                    __syncthreads();   // first iter: guards Af writes above
                    *(bf16x8*)&Bs[r1 * 40 + sac] = wv1;
                    *(bf16x8*)&Bs[r2 * 40 + sac] = wv2;
                    __syncthreads();

                    const bf16x8 af = *(const bf16x8*)&Af[(16 * wm + m16) * 136 + k0 + quad * 8];
                    bf16x8 bf[4];
                    #pragma unroll
                    for (int j = 0; j < 4; ++j)
                        bf[j] = *(const bf16x8*)&Bs[(64 * wn + 16 * j + m16) * 40 + quad * 8];
                    #pragma unroll
                    for (int j = 0; j < 4; ++j)
                        qacc[j] = __builtin_amdgcn_mfma_f32_16x16x32_bf16(af, bf[j], qacc[j], 0, 0, 0);
                }

                #pragma unroll
                for (int j = 0; j < 4; ++j) {
                    const int col = 64 * wn + 16 * j + m16;
                    const float bb = bias[col] * bscl;
                    const int hh = col >> 4, dh = col & 15;
                    #pragma unroll
                    for (int r = 0; r < 4; ++r) {
                        float val = fmaxf(qacc[j][r] + bb, 0.f);
                        const int gr = row0 + 16 * wm + quad * 4 + r;
                        const int b = gr >> 10, s = gr & 1023;
                        if (sel == 2) {
                            vo[(((size_t)b * Hq + hh) * DHq + dh) * Sq + s] = (_Float16)val;
                        } else {
                            _Float16* outp = (sel == 0) ? qo : ko;
                            outp[(((size_t)b * Hq + hh) * Sq + s) * DHq + dh] = (_Float16)val;
                        }
                    }
                }
            }
        }
    } else {
        // normalized rows -> vals2 (on dead Hs), then 32x6 projection
        #pragma unroll
        for (int j = 0; j < 4; ++j) {
            const int col = 64 * wn + 16 * j + m16;
            #pragma unroll
            for (int r = 0; r < 4; ++r) {
                const int row = 16 * wm + quad * 4 + r;
                vals2[row * 132 + col] =
                    (_Float16)(g2[col] * (vreg[j][r] - mus[row]) * rsds[row] + beta2[col]);
            }
        }
        __syncthreads();
        if (tid < 32 * NCLS) {
            const int row = tid / NCLS;
            const int c   = tid - row * NCLS;
            float a = bout[c];
            #pragma unroll 8
            for (int kk = 0; kk < Dq; ++kk)
                a = fmaf((float)vals2[row * 132 + kk], wo_s[kk * NCLS + c], a);
            out[(size_t)(row0 + row) * NCLS + c] = a;
        }
    }
}

// ---------------------------------------------------------------------------
// f16 MFMA flash attention (R15: qc=8, 2 Q-frags/wave, exp2_raw, f16 out).
// ---------------------------------------------------------------------------
__global__ __launch_bounds__(256) void attn_mfma(
    const _Float16* __restrict__ q, const _Float16* __restrict__ k,
    const _Float16* __restrict__ vt, _Float16* __restrict__ o)
{
    __shared__ _Float16 Ks[256 * 20];
    __shared__ _Float16 Vs[16 * 264];

    const int bh   = blockIdx.x;
    const int qc   = blockIdx.y;
    const int b    = bh >> 3;
    const int h    = bh & 7;
    const int tid  = threadIdx.x;
    const int wave = tid >> 6;
    const int lane = tid & 63;
    const int quad = lane >> 4;
    const int m16  = lane & 15;
    const int q0   = qc * 128 + wave * 32;

    const f16x4 qf0 = *(const f16x4*)(q + (((size_t)bh * Sq) + q0 + m16) * DHq + quad * 4);
    const f16x4 qf1 = *(const f16x4*)(q + (((size_t)bh * Sq) + q0 + 16 + m16) * DHq + quad * 4);

    const _Float16* kg  = k  + (size_t)bh * Sq * DHq;
    const _Float16* vtg = vt + (size_t)bh * DHq * Sq;

    f32x4 oacc0 = (f32x4)0.f, oacc1 = (f32x4)0.f;
    float lacc0 = 0.f, lacc1 = 0.f;

    const int krow = tid;
    const int vrow = tid >> 4;
    const int vcol = (tid & 15) * 16;

    for (int kb = 0; kb < 4; ++kb) {
        f16x8 ka  = *(const f16x8*)(kg + ((size_t)kb * 256 + krow) * DHq);
        f16x8 kb8 = *(const f16x8*)(kg + ((size_t)kb * 256 + krow) * DHq + 8);
        f16x8 va  = *(const f16x8*)(vtg + (size_t)vrow * Sq + kb * 256 + vcol);
        f16x8 vb  = *(const f16x8*)(vtg + (size_t)vrow * Sq + kb * 256 + vcol + 8);
        __syncthreads();
        *(f16x8*)&Ks[krow * 20 + 0] = ka;
        *(f16x8*)&Ks[krow * 20 + 8] = kb8;
        *(f16x8*)&Vs[vrow * 264 + vcol + 0] = va;
        *(f16x8*)&Vs[vrow * 264 + vcol + 8] = vb;
        __syncthreads();

        #pragma unroll 4
        for (int kt = 0; kt < 16; ++kt) {
            const f16x4 kf = *(const f16x4*)&Ks[(kt * 16 + m16) * 20 + quad * 4];
            const f16x4 vf = *(const f16x4*)&Vs[m16 * 264 + kt * 16 + quad * 4];

            f32x4 st0 = __builtin_amdgcn_mfma_f32_16x16x16f16(kf, qf0, (f32x4)0.f, 0, 0, 0);
            f32x4 st1 = __builtin_amdgcn_mfma_f32_16x16x16f16(kf, qf1, (f32x4)0.f, 0, 0, 0);

            float p00 = exp2_raw(st0[0]);
            float p01 = exp2_raw(st0[1]);
            float p02 = exp2_raw(st0[2]);
            float p03 = exp2_raw(st0[3]);
            float p10 = exp2_raw(st1[0]);
            float p11 = exp2_raw(st1[1]);
            float p12 = exp2_raw(st1[2]);
            float p13 = exp2_raw(st1[3]);
            lacc0 += (p00 + p01) + (p02 + p03);
            lacc1 += (p10 + p11) + (p12 + p13);

            f16x4 pf0, pf1;
            pf0[0] = (_Float16)p00; pf0[1] = (_Float16)p01;
            pf0[2] = (_Float16)p02; pf0[3] = (_Float16)p03;
            pf1[0] = (_Float16)p10; pf1[1] = (_Float16)p11;
            pf1[2] = (_Float16)p12; pf1[3] = (_Float16)p13;

            oacc0 = __builtin_amdgcn_mfma_f32_16x16x16f16(pf0, vf, oacc0, 0, 0, 0);
            oacc1 = __builtin_amdgcn_mfma_f32_16x16x16f16(pf1, vf, oacc1, 0, 0, 0);
        }
    }

    lacc0 += __shfl_xor(lacc0, 16, 64);
    lacc0 += __shfl_xor(lacc0, 32, 64);
    lacc1 += __shfl_xor(lacc1, 16, 64);
    lacc1 += __shfl_xor(lacc1, 32, 64);

    #pragma unroll
    for (int r = 0; r < 4; ++r) {
        const float ls0 = __shfl(lacc0, quad * 4 + r, 64);
        const float ls1 = __shfl(lacc1, quad * 4 + r, 64);
        o[((size_t)b * Sq + q0 + quad * 4 + r) * Dq + h * DHq + m16]      = (_Float16)(oacc0[r] / ls0);
        o[((size_t)b * Sq + q0 + 16 + quad * 4 + r) * Dq + h * DHq + m16] = (_Float16)(oacc1[r] / ls1);
    }
}

// ---------------------------------------------------------------------------
extern "C" void kernel_launch(void* const* d_in, const int* in_sizes, int n_in,
                              void* d_out, int out_size, void* d_ws, size_t ws_size,
                              hipStream_t stream)
{
    const float* x_in  = (const float*)d_in[0];
    const float* Wq    = (const float*)d_in[1];
    const float* bq    = (const float*)d_in[2];
    const float* Wk    = (const float*)d_in[3];
    const float* bk    = (const float*)d_in[4];
    const float* Wv    = (const float*)d_in[5];
    const float* bv    = (const float*)d_in[6];
    const float* ln1_g = (const float*)d_in[7];
    const float* ln1_b = (const float*)d_in[8];
    const float* W1    = (const float*)d_in[9];
    const float* b1    = (const float*)d_in[10];
    const float* W2    = (const float*)d_in[11];
    const float* b2    = (const float*)d_in[12];
    const float* ln2_g = (const float*)d_in[13];
    const float* ln2_b = (const float*)d_in[14];
    const float* Wout  = (const float*)d_in[15];
    const float* bout  = (const float*)d_in[16];
    float* out = (float*)d_out;

    float* ws = (float*)d_ws;
    _Float16* qf16 = (_Float16*)ws;                         // [0, 0.5NX)
    _Float16* kf16 = (_Float16*)(ws + NX / 2);              // [0.5, 1NX)
    _Float16* vt16 = (_Float16*)(ws + NX);                  // [1, 1.5NX)
    float*    xb   = ws + 9 * NX / 2;                       // [4.5, 5.5NX)
    ushort*   xbf0 = (ushort*)(ws + 11 * NX / 2);           // [5.5, 6NX)
    ushort*   wbf  = (ushort*)(ws + 7 * NX);                // [7, ~7.26NX)
    _Float16* obuf = (_Float16*)(ws + 8 * NX);              // [8, 8.25NX) f16

    prep_kernel<<<dim3(10304), dim3(256), 0, stream>>>(Wq, Wk, Wv, W1, W2, x_in, wbf, xbf0);

    const dim3 blk(256);

    // layer-0 QKV (from x cast)
    {
        const ushort* wqt = wbf + (size_t)0 * 16384;
        const ushort* wkt = wbf + (size_t)3 * 16384;
        const ushort* wvt = wbf + (size_t)6 * 16384;
        gemm_qkv<<<dim3(256, 3), blk, 0, stream>>>(
            xbf0, wqt, wkt, wvt, bq, bk, bv, qf16, kf16, vt16);
    }

    const float* xcur = x_in;
    for (int l = 0; l < Lq; ++l) {
        const ushort* w1t = wbf + 147456 + (size_t)l * 65536;
        const ushort* w2t = wbf + 344064 + (size_t)l * 65536;
        const int next = (l < Lq - 1) ? 1 : 0;
        const int ln   = l + 1;
        const ushort* wqn = next ? (wbf + (size_t)(0 * 3 + ln) * 16384) : wbf;
        const ushort* wkn = next ? (wbf + (size_t)(1 * 3 + ln) * 16384) : wbf;
        const ushort* wvn = next ? (wbf + (size_t)(2 * 3 + ln) * 16384) : wbf;
        const float*  bqn = next ? (bq + ln * Dq) : bq;
        const float*  bkn = next ? (bk + ln * Dq) : bk;
        const float*  bvn = next ? (bv + ln * Dq) : bv;

        attn_mfma<<<dim3(Bq * Hq, 8), blk, 0, stream>>>(qf16, kf16, vt16, obuf);

        gemm_ffn_fused<<<dim3(512), blk, 0, stream>>>(
            obuf, xcur, ln1_g + l * Dq, ln1_b + l * Dq,
            w1t, b1 + l * DFFq, w2t, b2 + l * Dq,
            ln2_g + l * Dq, ln2_b + l * Dq,
            xb,
            wqn, wkn, wvn, bqn, bkn, bvn,
            qf16, kf16, vt16, next,
            Wout, bout, out, (l == Lq - 1) ? 1 : 0);

        xcur = xb;
    }
}

// Round 17
// 256.365 us; speedup vs baseline: 1.0140x; 1.0140x over previous
//
#include <hip/hip_runtime.h>
#include <math.h>

#define Bq 16
#define Sq 1024
#define Dq 128
#define Hq 8
#define DHq 16
#define DFFq 512
#define Lq 3
#define NCLS 6
#define NROWS (Bq * Sq)       // 16384
#define NX ((size_t)NROWS * Dq)   // 2,097,152 floats

// Q pre-scale: (1/sqrt(DH)) * log2(e), so softmax probs = 2^score (raw v_exp)
#define QSCL 0.36067376022224085f

typedef __attribute__((ext_vector_type(8))) short    bf16x8;
typedef __attribute__((ext_vector_type(4))) float    f32x4;
typedef __attribute__((ext_vector_type(4))) _Float16 f16x4;
typedef __attribute__((ext_vector_type(8))) _Float16 f16x8;

__device__ inline ushort f32_to_bf16(float f) {
    union { float f; unsigned u; } v; v.f = f;
    unsigned r = v.u + 0x7fffu + ((v.u >> 16) & 1u);
    return (ushort)(r >> 16);
}

// raw 2^x via v_exp_f32 (ISA-guaranteed); avoids __expf's extra v_mul
__device__ __forceinline__ float exp2_raw(float x) {
    float r;
    asm("v_exp_f32 %0, %1" : "=v"(r) : "v"(x));
    return r;
}

// ---------------------------------------------------------------------------
// prep: cast+transpose weights to bf16 Wt[n][k]; cast x to bf16.
// Wq PRE-SCALED by QSCL (ReLU commutes with positive scale).
// ---------------------------------------------------------------------------
__global__ __launch_bounds__(256) void prep_kernel(
    const float* __restrict__ Wqp, const float* __restrict__ Wkp,
    const float* __restrict__ Wvp, const float* __restrict__ W1p,
    const float* __restrict__ W2p, const float* __restrict__ xp,
    ushort* __restrict__ wbf, ushort* __restrict__ xbf)
{
    const int gid = blockIdx.x * 256 + threadIdx.x;
    if (gid < 147456) {                       // QKV transpose
        const int w   = gid / 49152;
        const int rem = gid - w * 49152;
        const int l   = rem >> 14;
        const int idx = rem & 16383;
        const int k   = idx >> 7;
        const int n   = idx & 127;
        const float* src = (w == 0) ? Wqp : (w == 1) ? Wkp : Wvp;
        const float scl = (w == 0) ? QSCL : 1.0f;
        wbf[(size_t)(w * 3 + l) * 16384 + n * 128 + k] =
            f32_to_bf16(src[(size_t)l * 16384 + k * 128 + n] * scl);
    } else if (gid < 344064) {                // W1 [128][512]->[512][128]
        const int g   = gid - 147456;
        const int l   = g >> 16;
        const int idx = g & 65535;
        const int k   = idx >> 9;
        const int n   = idx & 511;
        wbf[147456 + (size_t)l * 65536 + n * 128 + k] =
            f32_to_bf16(W1p[(size_t)l * 65536 + k * 512 + n]);
    } else if (gid < 540672) {                // W2 [512][128]->[128][512]
        const int g   = gid - 344064;
        const int l   = g >> 16;
        const int idx = g & 65535;
        const int k   = idx >> 7;
        const int n   = idx & 127;
        wbf[344064 + (size_t)l * 65536 + n * 512 + k] =
            f32_to_bf16(W2p[(size_t)l * 65536 + k * 128 + n]);
    } else {                                  // x cast
        const int g = gid - 540672;
        xbf[g] = f32_to_bf16(xp[g]);
    }
}

// ---------------------------------------------------------------------------
// Standalone QKV GEMM (layer 0 only; R12-proven). grid (256, 3).
// ---------------------------------------------------------------------------
__global__ __launch_bounds__(256) void gemm_qkv(
    const ushort* __restrict__ A,
    const ushort* __restrict__ wq, const ushort* __restrict__ wk,
    const ushort* __restrict__ wv,
    const float* __restrict__ bqp, const float* __restrict__ bkp,
    const float* __restrict__ bvp,
    _Float16* __restrict__ qo, _Float16* __restrict__ ko,
    _Float16* __restrict__ vo)
{
    __shared__ ushort As[64 * 40];
    __shared__ ushort Bs[128 * 40];

    const int sel  = blockIdx.y;
    const ushort* Bt   = (sel == 0) ? wq : (sel == 1) ? wk : wv;
    const float*  bias = (sel == 0) ? bqp : (sel == 1) ? bkp : bvp;
    const float   bscl = (sel == 0) ? QSCL : 1.0f;

    const int tid  = threadIdx.x;
    const int row0 = blockIdx.x * 64;
    const int wave = tid >> 6;
    const int lane = tid & 63;
    const int quad = lane >> 4;
    const int m16  = lane & 15;
    const int wm   = wave >> 1;
    const int wn   = wave & 1;

    const int sar = tid >> 2;
    const int sac = (tid & 3) * 8;

    f32x4 acc[2][4];
    #pragma unroll
    for (int i = 0; i < 2; ++i)
        #pragma unroll
        for (int j = 0; j < 4; ++j) acc[i][j] = (f32x4)0.f;

    for (int k0 = 0; k0 < 128; k0 += 32) {
        bf16x8 av = *(const bf16x8*)(A + (size_t)(row0 + sar) * 128 + k0 + sac);
        const int r1 = tid >> 2, r2 = r1 + 64;
        bf16x8 bv1 = *(const bf16x8*)(Bt + (size_t)r1 * 128 + k0 + sac);
        bf16x8 bv2 = *(const bf16x8*)(Bt + (size_t)r2 * 128 + k0 + sac);

        __syncthreads();
        *(bf16x8*)&As[sar * 40 + sac] = av;
        *(bf16x8*)&Bs[r1 * 40 + sac]  = bv1;
        *(bf16x8*)&Bs[r2 * 40 + sac]  = bv2;
        __syncthreads();

        bf16x8 af[2], bf[4];
        #pragma unroll
        for (int i = 0; i < 2; ++i)
            af[i] = *(const bf16x8*)&As[(32 * wm + 16 * i + m16) * 40 + quad * 8];
        #pragma unroll
        for (int j = 0; j < 4; ++j)
            bf[j] = *(const bf16x8*)&Bs[(64 * wn + 16 * j + m16) * 40 + quad * 8];
        #pragma unroll
        for (int i = 0; i < 2; ++i)
            #pragma unroll
            for (int j = 0; j < 4; ++j)
                acc[i][j] = __builtin_amdgcn_mfma_f32_16x16x32_bf16(af[i], bf[j], acc[i][j], 0, 0, 0);
    }

    #pragma unroll
    for (int i = 0; i < 2; ++i) {
        #pragma unroll
        for (int j = 0; j < 4; ++j) {
            const int col = 64 * wn + 16 * j + m16;
            const float bb = bias[col] * bscl;
            const int hh = col >> 4, dh = col & 15;
            #pragma unroll
            for (int r = 0; r < 4; ++r) {
                float val = fmaxf(acc[i][j][r] + bb, 0.f);
                const int gr = row0 + 32 * wm + 16 * i + quad * 4 + r;
                const int b = gr >> 10, s = gr & 1023;
                if (sel == 2) {
                    vo[(((size_t)b * Hq + hh) * DHq + dh) * Sq + s] = (_Float16)val;
                } else {
                    _Float16* outp = (sel == 0) ? qo : ko;
                    outp[(((size_t)b * Hq + hh) * Sq + s) * DHq + dh] = (_Float16)val;
                }
            }
        }
    }
}

// ---------------------------------------------------------------------------
// FUSED FFN BLOCK v4 — R15's 64-K staging (16 barrier pairs) + R16's LDS diet
// (halved Hs, rreg residual). 44.3 KB LDS -> 3 blocks/CU.
//  - DFF in two 256-col halves; Hs 32x264; FFN2 acc2 accumulates across halves.
//  - Per half: FFN1 4 iters + FFN2 4 iters of 64-K staging (Bs 128x72).
//  - LN1 residual via transient r16 overlay on Bs -> registers.
//  + next-layer QKV epilogue (64-K staging, 2 iters/sel). o arrives f16.
// ---------------------------------------------------------------------------
__global__ __launch_bounds__(256, 3) void gemm_ffn_fused(
    const _Float16* __restrict__ o, const float* __restrict__ resid,
    const float* __restrict__ g1, const float* __restrict__ beta1,
    const ushort* __restrict__ W1t, const float* __restrict__ bias1,
    const ushort* __restrict__ W2t, const float* __restrict__ bias2,
    const float* __restrict__ g2, const float* __restrict__ beta2,
    float* __restrict__ xb,
    const ushort* __restrict__ wqn, const ushort* __restrict__ wkn,
    const ushort* __restrict__ wvn,
    const float* __restrict__ bqn, const float* __restrict__ bkn,
    const float* __restrict__ bvn,
    _Float16* __restrict__ qo, _Float16* __restrict__ ko,
    _Float16* __restrict__ vo, int do_next,
    const float* __restrict__ Wout, const float* __restrict__ bout,
    float* __restrict__ out, int last)
{
    __shared__ __align__(16) char smem[44288];
    ushort*    Af    = (ushort*)smem;                 // [0, 8704): 32x136 bf16
    ushort*    Hs    = (ushort*)(smem + 8704);        // [8704, 25600): 32x264 bf16
    ushort*    Bs    = (ushort*)(smem + 25600);       // [25600, 44032): 128x72
    _Float16*  r16   = (_Float16*)(smem + 25600);     // 32x132 f16 handoff (on Bs)
    _Float16*  vals2 = (_Float16*)(smem + 8704);      // 32x132 f16 exchange (on Hs)
    float*     wo_s  = (float*)(smem + 25600);        // last: 768 f32 (on Bs)
    float*     mus   = (float*)(smem + 44032);        // 32 f32
    float*     rsds  = (float*)(smem + 44160);        // 32 f32

    const int tid  = threadIdx.x;
    const int row0 = blockIdx.x * 32;
    const int wave = tid >> 6;
    const int lane = tid & 63;
    const int quad = lane >> 4;
    const int m16  = lane & 15;
    const int wm   = wave >> 1;          // row half: 16*wm
    const int wn   = wave & 1;           // col half: 64*wn
    const int sac  = (tid & 3) * 8;
    const int r1   = tid >> 2, r2 = r1 + 64;

    // ---- Phase A: LN1, 8 rows/wave, each row once ----
    #pragma unroll 2
    for (int it = 0; it < 8; ++it) {
        const int rr = wave * 8 + it;
        const size_t base = (size_t)(row0 + rr) * Dq;
        float v0 = (float)o[base + lane]      + resid[base + lane];
        float v1 = (float)o[base + 64 + lane] + resid[base + 64 + lane];

        float s = v0 + v1;
        #pragma unroll
        for (int off = 32; off > 0; off >>= 1) s += __shfl_xor(s, off, 64);
        const float mu = s * (1.f / 128.f);
        const float d0 = v0 - mu, d1 = v1 - mu;
        float vs = d0 * d0 + d1 * d1;
        #pragma unroll
        for (int off = 32; off > 0; off >>= 1) vs += __shfl_xor(vs, off, 64);
        const float rstd = rsqrtf(vs * (1.f / 128.f) + 1e-8f);

        const float rv0 = g1[lane]      * d0 * rstd + beta1[lane];
        const float rv1 = g1[lane + 64] * d1 * rstd + beta1[lane + 64];
        Af[rr * 136 + lane]       = f32_to_bf16(rv0);
        Af[rr * 136 + 64 + lane]  = f32_to_bf16(rv1);
        r16[rr * 132 + lane]      = (_Float16)rv0;
        r16[rr * 132 + 64 + lane] = (_Float16)rv1;
    }
    __syncthreads();

    // LN1 residual -> registers in Phase-D layout (r16 dies; Bs free)
    float rreg[4][4];
    #pragma unroll
    for (int j = 0; j < 4; ++j) {
        const int col = 64 * wn + 16 * j + m16;
        #pragma unroll
        for (int r = 0; r < 4; ++r)
            rreg[j][r] = (float)r16[(16 * wm + quad * 4 + r) * 132 + col];
    }

    // ---- Phases B+C, two DFF halves; acc2 accumulates across halves ----
    f32x4 acc2[4];
    #pragma unroll
    for (int j = 0; j < 4; ++j) acc2[j] = (f32x4)0.f;

    for (int half = 0; half < 2; ++half) {
        // FFN1 for output cols [half*256, half*256+256) -> Hs (local cols)
        f32x4 acc[4];
        #pragma unroll
        for (int j = 0; j < 4; ++j) acc[j] = (f32x4)0.f;

        for (int idx = 0; idx < 4; ++idx) {
            const int cc = idx >> 1;              // local col chunk 0/1
            const int k0 = (idx & 1) * 64;
            const int gc0 = half * 256 + cc * 128;

            bf16x8 w11 = *(const bf16x8*)(W1t + (size_t)(gc0 + r1) * 128 + k0 + sac);
            bf16x8 w12 = *(const bf16x8*)(W1t + (size_t)(gc0 + r1) * 128 + k0 + 32 + sac);
            bf16x8 w21 = *(const bf16x8*)(W1t + (size_t)(gc0 + r2) * 128 + k0 + sac);
            bf16x8 w22 = *(const bf16x8*)(W1t + (size_t)(gc0 + r2) * 128 + k0 + 32 + sac);

            __syncthreads();   // first iter also guards rreg reads above
            *(bf16x8*)&Bs[r1 * 72 + sac]      = w11;
            *(bf16x8*)&Bs[r1 * 72 + 32 + sac] = w12;
            *(bf16x8*)&Bs[r2 * 72 + sac]      = w21;
            *(bf16x8*)&Bs[r2 * 72 + 32 + sac] = w22;
            __syncthreads();

            #pragma unroll
            for (int hh = 0; hh < 2; ++hh) {
                const int kk = k0 + hh * 32;
                const bf16x8 af = *(const bf16x8*)&Af[(16 * wm + m16) * 136 + kk + quad * 8];
                bf16x8 bf[4];
                #pragma unroll
                for (int j = 0; j < 4; ++j)
                    bf[j] = *(const bf16x8*)&Bs[(64 * wn + 16 * j + m16) * 72 + hh * 32 + quad * 8];
                #pragma unroll
                for (int j = 0; j < 4; ++j)
                    acc[j] = __builtin_amdgcn_mfma_f32_16x16x32_bf16(af, bf[j], acc[j], 0, 0, 0);
            }

            if (idx & 1) {   // end of 128-col chunk: epilogue + reset
                #pragma unroll
                for (int j = 0; j < 4; ++j) {
                    const int lcol = cc * 128 + 64 * wn + 16 * j + m16;
                    const float bb = bias1[half * 256 + lcol];
                    #pragma unroll
                    for (int r = 0; r < 4; ++r) {
                        const int row = 16 * wm + quad * 4 + r;
                        Hs[row * 264 + lcol] = f32_to_bf16(fmaxf(acc[j][r] + bb, 0.f));
                    }
                    acc[j] = (f32x4)0.f;
                }
            }
        }

        // FFN2 partial: k in [half*256, half*256+256) from resident Hs
        for (int kc = 0; kc < 4; ++kc) {
            const int k0 = kc * 64;   // local k

            bf16x8 w11 = *(const bf16x8*)(W2t + (size_t)r1 * DFFq + half * 256 + k0 + sac);
            bf16x8 w12 = *(const bf16x8*)(W2t + (size_t)r1 * DFFq + half * 256 + k0 + 32 + sac);
            bf16x8 w21 = *(const bf16x8*)(W2t + (size_t)r2 * DFFq + half * 256 + k0 + sac);
            bf16x8 w22 = *(const bf16x8*)(W2t + (size_t)r2 * DFFq + half * 256 + k0 + 32 + sac);

            __syncthreads();   // kc==0: guards this half's Hs writes
            *(bf16x8*)&Bs[r1 * 72 + sac]      = w11;
            *(bf16x8*)&Bs[r1 * 72 + 32 + sac] = w12;
            *(bf16x8*)&Bs[r2 * 72 + sac]      = w21;
            *(bf16x8*)&Bs[r2 * 72 + 32 + sac] = w22;
            __syncthreads();

            #pragma unroll
            for (int hh = 0; hh < 2; ++hh) {
                const int kk = k0 + hh * 32;
                const bf16x8 af = *(const bf16x8*)&Hs[(16 * wm + m16) * 264 + kk + quad * 8];
                bf16x8 bf[4];
                #pragma unroll
                for (int j = 0; j < 4; ++j)
                    bf[j] = *(const bf16x8*)&Bs[(64 * wn + 16 * j + m16) * 72 + hh * 32 + quad * 8];
                #pragma unroll
                for (int j = 0; j < 4; ++j)
                    acc2[j] = __builtin_amdgcn_mfma_f32_16x16x32_bf16(af, bf[j], acc2[j], 0, 0, 0);
            }
        }
    }

    // ---- Phase D: +bias2 +LN1-residual (regs), LN2 ----
    __syncthreads();   // all Hs/Bs reads done; vals2 (on Hs) / wo_s (on Bs) safe

    float vreg[4][4];
    #pragma unroll
    for (int j = 0; j < 4; ++j) {
        const int col = 64 * wn + 16 * j + m16;
        const float bb = bias2[col];
        #pragma unroll
        for (int r = 0; r < 4; ++r) {
            const int row = 16 * wm + quad * 4 + r;
            float v = acc2[j][r] + bb + rreg[j][r];
            vreg[j][r] = v;
            vals2[row * 132 + col] = (_Float16)v;
        }
    }
    if (last) {
        #pragma unroll
        for (int i = 0; i < 3; ++i) wo_s[tid + i * 256] = Wout[tid + i * 256];
    }
    __syncthreads();

    if (tid < 32) {
        float s = 0.f, s2 = 0.f;
        #pragma unroll 8
        for (int c = 0; c < Dq; ++c) {
            float x = (float)vals2[tid * 132 + c];
            s += x; s2 = fmaf(x, x, s2);
        }
        const float mu  = s * (1.f / 128.f);
        const float var = s2 * (1.f / 128.f) - mu * mu;
        mus[tid]  = mu;
        rsds[tid] = rsqrtf(var + 1e-6f);
    }
    __syncthreads();

    if (!last) {
        // LN2 output: xb f32 (next-layer residual) + Af bf16 (A-operand for
        // the fused next-layer QKV below).
        #pragma unroll
        for (int j = 0; j < 4; ++j) {
            const int col = 64 * wn + 16 * j + m16;
            #pragma unroll
            for (int r = 0; r < 4; ++r) {
                const int row = 16 * wm + quad * 4 + r;
                const float rn = g2[col] * (vreg[j][r] - mus[row]) * rsds[row] + beta2[col];
                xb[(size_t)(row0 + row) * Dq + col] = rn;
                Af[row * 136 + col] = f32_to_bf16(rn);
            }
        }

        if (do_next) {
            // ---- next-layer QKV from resident Af (32 rows), 64-K staging ----
            for (int sel = 0; sel < 3; ++sel) {
                const ushort* Bt   = (sel == 0) ? wqn : (sel == 1) ? wkn : wvn;
                const float*  bias = (sel == 0) ? bqn : (sel == 1) ? bkn : bvn;
                const float   bscl = (sel == 0) ? QSCL : 1.0f;

                f32x4 qacc[4];
                #pragma unroll
                for (int j = 0; j < 4; ++j) qacc[j] = (f32x4)0.f;

                for (int kc = 0; kc < 2; ++kc) {
                    const int k0 = kc * 64;
                    bf16x8 w11 = *(const bf16x8*)(Bt + (size_t)r1 * 128 + k0 + sac);
                    bf16x8 w12 = *(const bf16x8*)(Bt + (size_t)r1 * 128 + k0 + 32 + sac);
                    bf16x8 w21 = *(const bf16x8*)(Bt + (size_t)r2 * 128 + k0 + sac);
                    bf16x8 w22 = *(const bf16x8*)(Bt + (size_t)r2 * 128 + k0 + 32 + sac);

                    __syncthreads();   // first iter: guards Af writes above
                    *(bf16x8*)&Bs[r1 * 72 + sac]      = w11;
                    *(bf16x8*)&Bs[r1 * 72 + 32 + sac] = w12;
                    *(bf16x8*)&Bs[r2 * 72 + sac]      = w21;
                    *(bf16x8*)&Bs[r2 * 72 + 32 + sac] = w22;
                    __syncthreads();

                    #pragma unroll
                    for (int hh = 0; hh < 2; ++hh) {
                        const int kk = k0 + hh * 32;
                        const bf16x8 af = *(const bf16x8*)&Af[(16 * wm + m16) * 136 + kk + quad * 8];
                        bf16x8 bf[4];
                        #pragma unroll
                        for (int j = 0; j < 4; ++j)
                            bf[j] = *(const bf16x8*)&Bs[(64 * wn + 16 * j + m16) * 72 + hh * 32 + quad * 8];
                        #pragma unroll
                        for (int j = 0; j < 4; ++j)
                            qacc[j] = __builtin_amdgcn_mfma_f32_16x16x32_bf16(af, bf[j], qacc[j], 0, 0, 0);
                    }
                }

                #pragma unroll
                for (int j = 0; j < 4; ++j) {
                    const int col = 64 * wn + 16 * j + m16;
                    const float bb = bias[col] * bscl;
                    const int hh = col >> 4, dh = col & 15;
                    #pragma unroll
                    for (int r = 0; r < 4; ++r) {
                        float val = fmaxf(qacc[j][r] + bb, 0.f);
                        const int gr = row0 + 16 * wm + quad * 4 + r;
                        const int b = gr >> 10, s = gr & 1023;
                        if (sel == 2) {
                            vo[(((size_t)b * Hq + hh) * DHq + dh) * Sq + s] = (_Float16)val;
                        } else {
                            _Float16* outp = (sel == 0) ? qo : ko;
                            outp[(((size_t)b * Hq + hh) * Sq + s) * DHq + dh] = (_Float16)val;
                        }
                    }
                }
            }
        }
    } else {
        // normalized rows -> vals2 (on dead Hs), then 32x6 projection
        #pragma unroll
        for (int j = 0; j < 4; ++j) {
            const int col = 64 * wn + 16 * j + m16;
            #pragma unroll
            for (int r = 0; r < 4; ++r) {
                const int row = 16 * wm + quad * 4 + r;
                vals2[row * 132 + col] =
                    (_Float16)(g2[col] * (vreg[j][r] - mus[row]) * rsds[row] + beta2[col]);
            }
        }
        __syncthreads();
        if (tid < 32 * NCLS) {
            const int row = tid / NCLS;
            const int c   = tid - row * NCLS;
            float a = bout[c];
            #pragma unroll 8
            for (int kk = 0; kk < Dq; ++kk)
                a = fmaf((float)vals2[row * 132 + kk], wo_s[kk * NCLS + c], a);
            out[(size_t)(row0 + row) * NCLS + c] = a;
        }
    }
}

// ---------------------------------------------------------------------------
// f16 MFMA flash attention (R15: qc=8, 2 Q-frags/wave, exp2_raw, f16 out).
// ---------------------------------------------------------------------------
__global__ __launch_bounds__(256) void attn_mfma(
    const _Float16* __restrict__ q, const _Float16* __restrict__ k,
    const _Float16* __restrict__ vt, _Float16* __restrict__ o)
{
    __shared__ _Float16 Ks[256 * 20];
    __shared__ _Float16 Vs[16 * 264];

    const int bh   = blockIdx.x;
    const int qc   = blockIdx.y;
    const int b    = bh >> 3;
    const int h    = bh & 7;
    const int tid  = threadIdx.x;
    const int wave = tid >> 6;
    const int lane = tid & 63;
    const int quad = lane >> 4;
    const int m16  = lane & 15;
    const int q0   = qc * 128 + wave * 32;

    const f16x4 qf0 = *(const f16x4*)(q + (((size_t)bh * Sq) + q0 + m16) * DHq + quad * 4);
    const f16x4 qf1 = *(const f16x4*)(q + (((size_t)bh * Sq) + q0 + 16 + m16) * DHq + quad * 4);

    const _Float16* kg  = k  + (size_t)bh * Sq * DHq;
    const _Float16* vtg = vt + (size_t)bh * DHq * Sq;

    f32x4 oacc0 = (f32x4)0.f, oacc1 = (f32x4)0.f;
    float lacc0 = 0.f, lacc1 = 0.f;

    const int krow = tid;
    const int vrow = tid >> 4;
    const int vcol = (tid & 15) * 16;

    for (int kb = 0; kb < 4; ++kb) {
        f16x8 ka  = *(const f16x8*)(kg + ((size_t)kb * 256 + krow) * DHq);
        f16x8 kb8 = *(const f16x8*)(kg + ((size_t)kb * 256 + krow) * DHq + 8);
        f16x8 va  = *(const f16x8*)(vtg + (size_t)vrow * Sq + kb * 256 + vcol);
        f16x8 vb  = *(const f16x8*)(vtg + (size_t)vrow * Sq + kb * 256 + vcol + 8);
        __syncthreads();
        *(f16x8*)&Ks[krow * 20 + 0] = ka;
        *(f16x8*)&Ks[krow * 20 + 8] = kb8;
        *(f16x8*)&Vs[vrow * 264 + vcol + 0] = va;
        *(f16x8*)&Vs[vrow * 264 + vcol + 8] = vb;
        __syncthreads();

        #pragma unroll 4
        for (int kt = 0; kt < 16; ++kt) {
            const f16x4 kf = *(const f16x4*)&Ks[(kt * 16 + m16) * 20 + quad * 4];
            const f16x4 vf = *(const f16x4*)&Vs[m16 * 264 + kt * 16 + quad * 4];

            f32x4 st0 = __builtin_amdgcn_mfma_f32_16x16x16f16(kf, qf0, (f32x4)0.f, 0, 0, 0);
            f32x4 st1 = __builtin_amdgcn_mfma_f32_16x16x16f16(kf, qf1, (f32x4)0.f, 0, 0, 0);

            float p00 = exp2_raw(st0[0]);
            float p01 = exp2_raw(st0[1]);
            float p02 = exp2_raw(st0[2]);
            float p03 = exp2_raw(st0[3]);
            float p10 = exp2_raw(st1[0]);
            float p11 = exp2_raw(st1[1]);
            float p12 = exp2_raw(st1[2]);
            float p13 = exp2_raw(st1[3]);
            lacc0 += (p00 + p01) + (p02 + p03);
            lacc1 += (p10 + p11) + (p12 + p13);

            f16x4 pf0, pf1;
            pf0[0] = (_Float16)p00; pf0[1] = (_Float16)p01;
            pf0[2] = (_Float16)p02; pf0[3] = (_Float16)p03;
            pf1[0] = (_Float16)p10; pf1[1] = (_Float16)p11;
            pf1[2] = (_Float16)p12; pf1[3] = (_Float16)p13;

            oacc0 = __builtin_amdgcn_mfma_f32_16x16x16f16(pf0, vf, oacc0, 0, 0, 0);
            oacc1 = __builtin_amdgcn_mfma_f32_16x16x16f16(pf1, vf, oacc1, 0, 0, 0);
        }
    }

    lacc0 += __shfl_xor(lacc0, 16, 64);
    lacc0 += __shfl_xor(lacc0, 32, 64);
    lacc1 += __shfl_xor(lacc1, 16, 64);
    lacc1 += __shfl_xor(lacc1, 32, 64);

    #pragma unroll
    for (int r = 0; r < 4; ++r) {
        const float ls0 = __shfl(lacc0, quad * 4 + r, 64);
        const float ls1 = __shfl(lacc1, quad * 4 + r, 64);
        o[((size_t)b * Sq + q0 + quad * 4 + r) * Dq + h * DHq + m16]      = (_Float16)(oacc0[r] / ls0);
        o[((size_t)b * Sq + q0 + 16 + quad * 4 + r) * Dq + h * DHq + m16] = (_Float16)(oacc1[r] / ls1);
    }
}

// ---------------------------------------------------------------------------
extern "C" void kernel_launch(void* const* d_in, const int* in_sizes, int n_in,
                              void* d_out, int out_size, void* d_ws, size_t ws_size,
                              hipStream_t stream)
{
    const float* x_in  = (const float*)d_in[0];
    const float* Wq    = (const float*)d_in[1];
    const float* bq    = (const float*)d_in[2];
    const float* Wk    = (const float*)d_in[3];
    const float* bk    = (const float*)d_in[4];
    const float* Wv    = (const float*)d_in[5];
    const float* bv    = (const float*)d_in[6];
    const float* ln1_g = (const float*)d_in[7];
    const float* ln1_b = (const float*)d_in[8];
    const float* W1    = (const float*)d_in[9];
    const float* b1    = (const float*)d_in[10];
    const float* W2    = (const float*)d_in[11];
    const float* b2    = (const float*)d_in[12];
    const float* ln2_g = (const float*)d_in[13];
    const float* ln2_b = (const float*)d_in[14];
    const float* Wout  = (const float*)d_in[15];
    const float* bout  = (const float*)d_in[16];
    float* out = (float*)d_out;

    float* ws = (float*)d_ws;
    _Float16* qf16 = (_Float16*)ws;                         // [0, 0.5NX)
    _Float16* kf16 = (_Float16*)(ws + NX / 2);              // [0.5, 1NX)
    _Float16* vt16 = (_Float16*)(ws + NX);                  // [1, 1.5NX)
    float*    xb   = ws + 9 * NX / 2;                       // [4.5, 5.5NX)
    ushort*   xbf0 = (ushort*)(ws + 11 * NX / 2);           // [5.5, 6NX)
    ushort*   wbf  = (ushort*)(ws + 7 * NX);                // [7, ~7.26NX)
    _Float16* obuf = (_Float16*)(ws + 8 * NX);              // [8, 8.25NX) f16

    prep_kernel<<<dim3(10304), dim3(256), 0, stream>>>(Wq, Wk, Wv, W1, W2, x_in, wbf, xbf0);

    const dim3 blk(256);

    // layer-0 QKV (from x cast)
    {
        const ushort* wqt = wbf + (size_t)0 * 16384;
        const ushort* wkt = wbf + (size_t)3 * 16384;
        const ushort* wvt = wbf + (size_t)6 * 16384;
        gemm_qkv<<<dim3(256, 3), blk, 0, stream>>>(
            xbf0, wqt, wkt, wvt, bq, bk, bv, qf16, kf16, vt16);
    }

    const float* xcur = x_in;
    for (int l = 0; l < Lq; ++l) {
        const ushort* w1t = wbf + 147456 + (size_t)l * 65536;
        const ushort* w2t = wbf + 344064 + (size_t)l * 65536;
        const int next = (l < Lq - 1) ? 1 : 0;
        const int ln   = l + 1;
        const ushort* wqn = next ? (wbf + (size_t)(0 * 3 + ln) * 16384) : wbf;
        const ushort* wkn = next ? (wbf + (size_t)(1 * 3 + ln) * 16384) : wbf;
        const ushort* wvn = next ? (wbf + (size_t)(2 * 3 + ln) * 16384) : wbf;
        const float*  bqn = next ? (bq + ln * Dq) : bq;
        const float*  bkn = next ? (bk + ln * Dq) : bk;
        const float*  bvn = next ? (bv + ln * Dq) : bv;

        attn_mfma<<<dim3(Bq * Hq, 8), blk, 0, stream>>>(qf16, kf16, vt16, obuf);

        gemm_ffn_fused<<<dim3(512), blk, 0, stream>>>(
            obuf, xcur, ln1_g + l * Dq, ln1_b + l * Dq,
            w1t, b1 + l * DFFq, w2t, b2 + l * Dq,
            ln2_g + l * Dq, ln2_b + l * Dq,
            xb,
            wqn, wkn, wvn, bqn, bkn, bvn,
            qf16, kf16, vt16, next,
            Wout, bout, out, (l == Lq - 1) ? 1 : 0);

        xcur = xb;
    }
}

// Round 18
// 256.084 us; speedup vs baseline: 1.0151x; 1.0011x over previous
//
#include <hip/hip_runtime.h>
#include <math.h>

#define Bq 16
#define Sq 1024
#define Dq 128
#define Hq 8
#define DHq 16
#define DFFq 512
#define Lq 3
#define NCLS 6
#define NROWS (Bq * Sq)       // 16384
#define NX ((size_t)NROWS * Dq)   // 2,097,152 floats

// Q pre-scale: (1/sqrt(DH)) * log2(e), so softmax probs = 2^score (raw v_exp)
#define QSCL 0.36067376022224085f

typedef __attribute__((ext_vector_type(8))) short    bf16x8;
typedef __attribute__((ext_vector_type(4))) float    f32x4;
typedef __attribute__((ext_vector_type(4))) _Float16 f16x4;
typedef __attribute__((ext_vector_type(8))) _Float16 f16x8;

__device__ inline ushort f32_to_bf16(float f) {
    union { float f; unsigned u; } v; v.f = f;
    unsigned r = v.u + 0x7fffu + ((v.u >> 16) & 1u);
    return (ushort)(r >> 16);
}

// raw 2^x via v_exp_f32 (ISA-guaranteed); avoids __expf's extra v_mul
__device__ __forceinline__ float exp2_raw(float x) {
    float r;
    asm("v_exp_f32 %0, %1" : "=v"(r) : "v"(x));
    return r;
}

// ---------------------------------------------------------------------------
// prep: cast+transpose weights to bf16 Wt[n][k]; cast x to bf16.
// Wq PRE-SCALED by QSCL (ReLU commutes with positive scale).
// ---------------------------------------------------------------------------
__global__ __launch_bounds__(256) void prep_kernel(
    const float* __restrict__ Wqp, const float* __restrict__ Wkp,
    const float* __restrict__ Wvp, const float* __restrict__ W1p,
    const float* __restrict__ W2p, const float* __restrict__ xp,
    ushort* __restrict__ wbf, ushort* __restrict__ xbf)
{
    const int gid = blockIdx.x * 256 + threadIdx.x;
    if (gid < 147456) {                       // QKV transpose
        const int w   = gid / 49152;
        const int rem = gid - w * 49152;
        const int l   = rem >> 14;
        const int idx = rem & 16383;
        const int k   = idx >> 7;
        const int n   = idx & 127;
        const float* src = (w == 0) ? Wqp : (w == 1) ? Wkp : Wvp;
        const float scl = (w == 0) ? QSCL : 1.0f;
        wbf[(size_t)(w * 3 + l) * 16384 + n * 128 + k] =
            f32_to_bf16(src[(size_t)l * 16384 + k * 128 + n] * scl);
    } else if (gid < 344064) {                // W1 [128][512]->[512][128]
        const int g   = gid - 147456;
        const int l   = g >> 16;
        const int idx = g & 65535;
        const int k   = idx >> 9;
        const int n   = idx & 511;
        wbf[147456 + (size_t)l * 65536 + n * 128 + k] =
            f32_to_bf16(W1p[(size_t)l * 65536 + k * 512 + n]);
    } else if (gid < 540672) {                // W2 [512][128]->[128][512]
        const int g   = gid - 344064;
        const int l   = g >> 16;
        const int idx = g & 65535;
        const int k   = idx >> 7;
        const int n   = idx & 127;
        wbf[344064 + (size_t)l * 65536 + n * 512 + k] =
            f32_to_bf16(W2p[(size_t)l * 65536 + k * 128 + n]);
    } else {                                  // x cast
        const int g = gid - 540672;
        xbf[g] = f32_to_bf16(xp[g]);
    }
}

// ---------------------------------------------------------------------------
// Standalone QKV GEMM (layer 0 only; R12-proven). grid (256, 3).
// ---------------------------------------------------------------------------
__global__ __launch_bounds__(256) void gemm_qkv(
    const ushort* __restrict__ A,
    const ushort* __restrict__ wq, const ushort* __restrict__ wk,
    const ushort* __restrict__ wv,
    const float* __restrict__ bqp, const float* __restrict__ bkp,
    const float* __restrict__ bvp,
    _Float16* __restrict__ qo, _Float16* __restrict__ ko,
    _Float16* __restrict__ vo)
{
    __shared__ ushort As[64 * 40];
    __shared__ ushort Bs[128 * 40];

    const int sel  = blockIdx.y;
    const ushort* Bt   = (sel == 0) ? wq : (sel == 1) ? wk : wv;
    const float*  bias = (sel == 0) ? bqp : (sel == 1) ? bkp : bvp;
    const float   bscl = (sel == 0) ? QSCL : 1.0f;

    const int tid  = threadIdx.x;
    const int row0 = blockIdx.x * 64;
    const int wave = tid >> 6;
    const int lane = tid & 63;
    const int quad = lane >> 4;
    const int m16  = lane & 15;
    const int wm   = wave >> 1;
    const int wn   = wave & 1;

    const int sar = tid >> 2;
    const int sac = (tid & 3) * 8;

    f32x4 acc[2][4];
    #pragma unroll
    for (int i = 0; i < 2; ++i)
        #pragma unroll
        for (int j = 0; j < 4; ++j) acc[i][j] = (f32x4)0.f;

    for (int k0 = 0; k0 < 128; k0 += 32) {
        bf16x8 av = *(const bf16x8*)(A + (size_t)(row0 + sar) * 128 + k0 + sac);
        const int r1 = tid >> 2, r2 = r1 + 64;
        bf16x8 bv1 = *(const bf16x8*)(Bt + (size_t)r1 * 128 + k0 + sac);
        bf16x8 bv2 = *(const bf16x8*)(Bt + (size_t)r2 * 128 + k0 + sac);

        __syncthreads();
        *(bf16x8*)&As[sar * 40 + sac] = av;
        *(bf16x8*)&Bs[r1 * 40 + sac]  = bv1;
        *(bf16x8*)&Bs[r2 * 40 + sac]  = bv2;
        __syncthreads();

        bf16x8 af[2], bf[4];
        #pragma unroll
        for (int i = 0; i < 2; ++i)
            af[i] = *(const bf16x8*)&As[(32 * wm + 16 * i + m16) * 40 + quad * 8];
        #pragma unroll
        for (int j = 0; j < 4; ++j)
            bf[j] = *(const bf16x8*)&Bs[(64 * wn + 16 * j + m16) * 40 + quad * 8];
        #pragma unroll
        for (int i = 0; i < 2; ++i)
            #pragma unroll
            for (int j = 0; j < 4; ++j)
                acc[i][j] = __builtin_amdgcn_mfma_f32_16x16x32_bf16(af[i], bf[j], acc[i][j], 0, 0, 0);
    }

    #pragma unroll
    for (int i = 0; i < 2; ++i) {
        #pragma unroll
        for (int j = 0; j < 4; ++j) {
            const int col = 64 * wn + 16 * j + m16;
            const float bb = bias[col] * bscl;
            const int hh = col >> 4, dh = col & 15;
            #pragma unroll
            for (int r = 0; r < 4; ++r) {
                float val = fmaxf(acc[i][j][r] + bb, 0.f);
                const int gr = row0 + 32 * wm + 16 * i + quad * 4 + r;
                const int b = gr >> 10, s = gr & 1023;
                if (sel == 2) {
                    vo[(((size_t)b * Hq + hh) * DHq + dh) * Sq + s] = (_Float16)val;
                } else {
                    _Float16* outp = (sel == 0) ? qo : ko;
                    outp[(((size_t)b * Hq + hh) * Sq + s) * DHq + dh] = (_Float16)val;
                }
            }
        }
    }
}

// ---------------------------------------------------------------------------
// FUSED FFN BLOCK (R14-proven: LN1 -> FFN1 -> FFN2 -> LN2 + next-layer QKV
// in the epilogue). o (attention output) arrives as f16. 69 KB LDS,
// 2 blocks/CU — measured optimum (R16/R17 occupancy experiments both lost).
// ---------------------------------------------------------------------------
__global__ __launch_bounds__(256) void gemm_ffn_fused(
    const _Float16* __restrict__ o, const float* __restrict__ resid,
    const float* __restrict__ g1, const float* __restrict__ beta1,
    const ushort* __restrict__ W1t, const float* __restrict__ bias1,
    const ushort* __restrict__ W2t, const float* __restrict__ bias2,
    const float* __restrict__ g2, const float* __restrict__ beta2,
    float* __restrict__ xb,
    const ushort* __restrict__ wqn, const ushort* __restrict__ wkn,
    const ushort* __restrict__ wvn,
    const float* __restrict__ bqn, const float* __restrict__ bkn,
    const float* __restrict__ bvn,
    _Float16* __restrict__ qo, _Float16* __restrict__ ko,
    _Float16* __restrict__ vo, int do_next,
    const float* __restrict__ Wout, const float* __restrict__ bout,
    float* __restrict__ out, int last)
{
    __shared__ __align__(16) char smem[69120];
    ushort*    Af   = (ushort*)smem;                 // 32x136 bf16
    ushort*    Hs   = (ushort*)(smem + 8704);        // 32x520 bf16
    ushort*    Bs   = (ushort*)(smem + 41984);       // 128x72 staging
    float*     wo_s = (float*)(smem + 41984);        // overlays Bs in phase D(last)
    _Float16*  vals = (_Float16*)(smem + 60416);     // 32x132 f16
    float*     mus  = (float*)(smem + 68864);
    float*     rsds = (float*)(smem + 68992);

    const int tid  = threadIdx.x;
    const int row0 = blockIdx.x * 32;
    const int wave = tid >> 6;
    const int lane = tid & 63;
    const int quad = lane >> 4;
    const int m16  = lane & 15;
    const int wm   = wave >> 1;          // row half: 16*wm
    const int wn   = wave & 1;           // col half: 64*wn
    const int sac  = (tid & 3) * 8;
    const int r1   = tid >> 2, r2 = r1 + 64;

    // ---- Phase A: LN1, 8 rows/wave, each row once ----
    #pragma unroll 2
    for (int it = 0; it < 8; ++it) {
        const int rr = wave * 8 + it;
        const size_t base = (size_t)(row0 + rr) * Dq;
        float v0 = (float)o[base + lane]      + resid[base + lane];
        float v1 = (float)o[base + 64 + lane] + resid[base + 64 + lane];

        float s = v0 + v1;
        #pragma unroll
        for (int off = 32; off > 0; off >>= 1) s += __shfl_xor(s, off, 64);
        const float mu = s * (1.f / 128.f);
        const float d0 = v0 - mu, d1 = v1 - mu;
        float vs = d0 * d0 + d1 * d1;
        #pragma unroll
        for (int off = 32; off > 0; off >>= 1) vs += __shfl_xor(vs, off, 64);
        const float rstd = rsqrtf(vs * (1.f / 128.f) + 1e-8f);

        const float rv0 = g1[lane]      * d0 * rstd + beta1[lane];
        const float rv1 = g1[lane + 64] * d1 * rstd + beta1[lane + 64];
        Af[rr * 136 + lane]        = f32_to_bf16(rv0);
        Af[rr * 136 + 64 + lane]   = f32_to_bf16(rv1);
        vals[rr * 132 + lane]      = (_Float16)rv0;
        vals[rr * 132 + 64 + lane] = (_Float16)rv1;
    }

    // ---- Phase B: FFN1 (8 iters of 64-K), h -> Hs ----
    f32x4 acc[4];
    #pragma unroll
    for (int j = 0; j < 4; ++j) acc[j] = (f32x4)0.f;

    for (int idx = 0; idx < 8; ++idx) {
        const int cc = idx >> 1;
        const int k0 = (idx & 1) * 64;

        bf16x8 w11 = *(const bf16x8*)(W1t + (size_t)(cc * 128 + r1) * 128 + k0 + sac);
        bf16x8 w12 = *(const bf16x8*)(W1t + (size_t)(cc * 128 + r1) * 128 + k0 + 32 + sac);
        bf16x8 w21 = *(const bf16x8*)(W1t + (size_t)(cc * 128 + r2) * 128 + k0 + sac);
        bf16x8 w22 = *(const bf16x8*)(W1t + (size_t)(cc * 128 + r2) * 128 + k0 + 32 + sac);

        __syncthreads();   // idx==0: also guards Phase-A LDS writes
        *(bf16x8*)&Bs[r1 * 72 + sac]      = w11;
        *(bf16x8*)&Bs[r1 * 72 + 32 + sac] = w12;
        *(bf16x8*)&Bs[r2 * 72 + sac]      = w21;
        *(bf16x8*)&Bs[r2 * 72 + 32 + sac] = w22;
        __syncthreads();

        #pragma unroll
        for (int hh = 0; hh < 2; ++hh) {
            const int kk = k0 + hh * 32;
            const bf16x8 af = *(const bf16x8*)&Af[(16 * wm + m16) * 136 + kk + quad * 8];
            bf16x8 bf[4];
            #pragma unroll
            for (int j = 0; j < 4; ++j)
                bf[j] = *(const bf16x8*)&Bs[(64 * wn + 16 * j + m16) * 72 + hh * 32 + quad * 8];
            #pragma unroll
            for (int j = 0; j < 4; ++j)
                acc[j] = __builtin_amdgcn_mfma_f32_16x16x32_bf16(af, bf[j], acc[j], 0, 0, 0);
        }

        if (idx & 1) {
            #pragma unroll
            for (int j = 0; j < 4; ++j) {
                const int col = cc * 128 + 64 * wn + 16 * j + m16;
                const float bb = bias1[col];
                #pragma unroll
                for (int r = 0; r < 4; ++r) {
                    const int row = 16 * wm + quad * 4 + r;
                    Hs[row * 520 + col] = f32_to_bf16(fmaxf(acc[j][r] + bb, 0.f));
                }
                acc[j] = (f32x4)0.f;
            }
        }
    }

    // ---- Phase C: FFN2 (8 iters of 64-K) from resident Hs ----
    f32x4 acc2[4];
    #pragma unroll
    for (int j = 0; j < 4; ++j) acc2[j] = (f32x4)0.f;

    for (int kc = 0; kc < 8; ++kc) {
        const int k0 = kc * 64;

        bf16x8 w11 = *(const bf16x8*)(W2t + (size_t)r1 * DFFq + k0 + sac);
        bf16x8 w12 = *(const bf16x8*)(W2t + (size_t)r1 * DFFq + k0 + 32 + sac);
        bf16x8 w21 = *(const bf16x8*)(W2t + (size_t)r2 * DFFq + k0 + sac);
        bf16x8 w22 = *(const bf16x8*)(W2t + (size_t)r2 * DFFq + k0 + 32 + sac);

        __syncthreads();   // kc==0: also guards Phase-B Hs writes
        *(bf16x8*)&Bs[r1 * 72 + sac]      = w11;
        *(bf16x8*)&Bs[r1 * 72 + 32 + sac] = w12;
        *(bf16x8*)&Bs[r2 * 72 + sac]      = w21;
        *(bf16x8*)&Bs[r2 * 72 + 32 + sac] = w22;
        __syncthreads();

        #pragma unroll
        for (int hh = 0; hh < 2; ++hh) {
            const int kk = k0 + hh * 32;
            const bf16x8 af = *(const bf16x8*)&Hs[(16 * wm + m16) * 520 + kk + quad * 8];
            bf16x8 bf[4];
            #pragma unroll
            for (int j = 0; j < 4; ++j)
                bf[j] = *(const bf16x8*)&Bs[(64 * wn + 16 * j + m16) * 72 + hh * 32 + quad * 8];
            #pragma unroll
            for (int j = 0; j < 4; ++j)
                acc2[j] = __builtin_amdgcn_mfma_f32_16x16x32_bf16(af, bf[j], acc2[j], 0, 0, 0);
        }
    }

    // ---- Phase D: +bias2 +LN1-residual (vals), LN2 ----
    __syncthreads();

    float vreg[4][4];
    #pragma unroll
    for (int j = 0; j < 4; ++j) {
        const int col = 64 * wn + 16 * j + m16;
        const float bb = bias2[col];
        #pragma unroll
        for (int r = 0; r < 4; ++r) {
            const int row = 16 * wm + quad * 4 + r;
            float v = acc2[j][r] + bb + (float)vals[row * 132 + col];
            vreg[j][r] = v;
            vals[row * 132 + col] = (_Float16)v;
        }
    }
    if (last) {
        #pragma unroll
        for (int i = 0; i < 3; ++i) wo_s[tid + i * 256] = Wout[tid + i * 256];
    }
    __syncthreads();

    if (tid < 32) {
        float s = 0.f, s2 = 0.f;
        #pragma unroll 8
        for (int c = 0; c < Dq; ++c) {
            float x = (float)vals[tid * 132 + c];
            s += x; s2 = fmaf(x, x, s2);
        }
        const float mu  = s * (1.f / 128.f);
        const float var = s2 * (1.f / 128.f) - mu * mu;
        mus[tid]  = mu;
        rsds[tid] = rsqrtf(var + 1e-6f);
    }
    __syncthreads();

    if (!last) {
        // LN2 output: xb f32 (next-layer residual) + Af bf16 (A-operand for
        // the fused next-layer QKV below).
        #pragma unroll
        for (int j = 0; j < 4; ++j) {
            const int col = 64 * wn + 16 * j + m16;
            #pragma unroll
            for (int r = 0; r < 4; ++r) {
                const int row = 16 * wm + quad * 4 + r;
                const float rn = g2[col] * (vreg[j][r] - mus[row]) * rsds[row] + beta2[col];
                xb[(size_t)(row0 + row) * Dq + col] = rn;
                Af[row * 136 + col] = f32_to_bf16(rn);
            }
        }

        if (do_next) {
            // ---- next-layer QKV from resident Af (32 rows), 64-K staging ----
            for (int sel = 0; sel < 3; ++sel) {
                const ushort* Bt   = (sel == 0) ? wqn : (sel == 1) ? wkn : wvn;
                const float*  bias = (sel == 0) ? bqn : (sel == 1) ? bkn : bvn;
                const float   bscl = (sel == 0) ? QSCL : 1.0f;

                f32x4 qacc[4];
                #pragma unroll
                for (int j = 0; j < 4; ++j) qacc[j] = (f32x4)0.f;

                for (int half = 0; half < 2; ++half) {
                    const int k0 = half * 64;
                    bf16x8 w11 = *(const bf16x8*)(Bt + (size_t)r1 * 128 + k0 + sac);
                    bf16x8 w12 = *(const bf16x8*)(Bt + (size_t)r1 * 128 + k0 + 32 + sac);
                    bf16x8 w21 = *(const bf16x8*)(Bt + (size_t)r2 * 128 + k0 + sac);
                    bf16x8 w22 = *(const bf16x8*)(Bt + (size_t)r2 * 128 + k0 + 32 + sac);

                    __syncthreads();   // first iter: guards Af writes above
                    *(bf16x8*)&Bs[r1 * 72 + sac]      = w11;
                    *(bf16x8*)&Bs[r1 * 72 + 32 + sac] = w12;
                    *(bf16x8*)&Bs[r2 * 72 + sac]      = w21;
                    *(bf16x8*)&Bs[r2 * 72 + 32 + sac] = w22;
                    __syncthreads();

                    #pragma unroll
                    for (int hh = 0; hh < 2; ++hh) {
                        const int kk = k0 + hh * 32;
                        const bf16x8 af = *(const bf16x8*)&Af[(16 * wm + m16) * 136 + kk + quad * 8];
                        bf16x8 bf[4];
                        #pragma unroll
                        for (int j = 0; j < 4; ++j)
                            bf[j] = *(const bf16x8*)&Bs[(64 * wn + 16 * j + m16) * 72 + hh * 32 + quad * 8];
                        #pragma unroll
                        for (int j = 0; j < 4; ++j)
                            qacc[j] = __builtin_amdgcn_mfma_f32_16x16x32_bf16(af, bf[j], qacc[j], 0, 0, 0);
                    }
                }

                #pragma unroll
                for (int j = 0; j < 4; ++j) {
                    const int col = 64 * wn + 16 * j + m16;
                    const float bb = bias[col] * bscl;
                    const int hh = col >> 4, dh = col & 15;
                    #pragma unroll
                    for (int r = 0; r < 4; ++r) {
                        float val = fmaxf(qacc[j][r] + bb, 0.f);
                        const int gr = row0 + 16 * wm + quad * 4 + r;
                        const int b = gr >> 10, s = gr & 1023;
                        if (sel == 2) {
                            vo[(((size_t)b * Hq + hh) * DHq + dh) * Sq + s] = (_Float16)val;
                        } else {
                            _Float16* outp = (sel == 0) ? qo : ko;
                            outp[(((size_t)b * Hq + hh) * Sq + s) * DHq + dh] = (_Float16)val;
                        }
                    }
                }
            }
        }
    } else {
        #pragma unroll
        for (int j = 0; j < 4; ++j) {
            const int col = 64 * wn + 16 * j + m16;
            #pragma unroll
            for (int r = 0; r < 4; ++r) {
                const int row = 16 * wm + quad * 4 + r;
                vals[row * 132 + col] =
                    (_Float16)(g2[col] * (vreg[j][r] - mus[row]) * rsds[row] + beta2[col]);
            }
        }
        __syncthreads();
        if (tid < 32 * NCLS) {
            const int row = tid / NCLS;
            const int c   = tid - row * NCLS;
            float a = bout[c];
            #pragma unroll 8
            for (int kk = 0; kk < Dq; ++kk)
                a = fmaf((float)vals[row * 132 + kk], wo_s[kk * NCLS + c], a);
            out[(size_t)(row0 + row) * NCLS + c] = a;
        }
    }
}

// ---------------------------------------------------------------------------
// f16 MFMA flash attention (R15: qc=8, 2 Q-frags/wave, exp2_raw, f16 out).
// ---------------------------------------------------------------------------
__global__ __launch_bounds__(256) void attn_mfma(
    const _Float16* __restrict__ q, const _Float16* __restrict__ k,
    const _Float16* __restrict__ vt, _Float16* __restrict__ o)
{
    __shared__ _Float16 Ks[256 * 20];
    __shared__ _Float16 Vs[16 * 264];

    const int bh   = blockIdx.x;
    const int qc   = blockIdx.y;
    const int b    = bh >> 3;
    const int h    = bh & 7;
    const int tid  = threadIdx.x;
    const int wave = tid >> 6;
    const int lane = tid & 63;
    const int quad = lane >> 4;
    const int m16  = lane & 15;
    const int q0   = qc * 128 + wave * 32;

    const f16x4 qf0 = *(const f16x4*)(q + (((size_t)bh * Sq) + q0 + m16) * DHq + quad * 4);
    const f16x4 qf1 = *(const f16x4*)(q + (((size_t)bh * Sq) + q0 + 16 + m16) * DHq + quad * 4);

    const _Float16* kg  = k  + (size_t)bh * Sq * DHq;
    const _Float16* vtg = vt + (size_t)bh * DHq * Sq;

    f32x4 oacc0 = (f32x4)0.f, oacc1 = (f32x4)0.f;
    float lacc0 = 0.f, lacc1 = 0.f;

    const int krow = tid;
    const int vrow = tid >> 4;
    const int vcol = (tid & 15) * 16;

    for (int kb = 0; kb < 4; ++kb) {
        f16x8 ka  = *(const f16x8*)(kg + ((size_t)kb * 256 + krow) * DHq);
        f16x8 kb8 = *(const f16x8*)(kg + ((size_t)kb * 256 + krow) * DHq + 8);
        f16x8 va  = *(const f16x8*)(vtg + (size_t)vrow * Sq + kb * 256 + vcol);
        f16x8 vb  = *(const f16x8*)(vtg + (size_t)vrow * Sq + kb * 256 + vcol + 8);
        __syncthreads();
        *(f16x8*)&Ks[krow * 20 + 0] = ka;
        *(f16x8*)&Ks[krow * 20 + 8] = kb8;
        *(f16x8*)&Vs[vrow * 264 + vcol + 0] = va;
        *(f16x8*)&Vs[vrow * 264 + vcol + 8] = vb;
        __syncthreads();

        #pragma unroll 4
        for (int kt = 0; kt < 16; ++kt) {
            const f16x4 kf = *(const f16x4*)&Ks[(kt * 16 + m16) * 20 + quad * 4];
            const f16x4 vf = *(const f16x4*)&Vs[m16 * 264 + kt * 16 + quad * 4];

            f32x4 st0 = __builtin_amdgcn_mfma_f32_16x16x16f16(kf, qf0, (f32x4)0.f, 0, 0, 0);
            f32x4 st1 = __builtin_amdgcn_mfma_f32_16x16x16f16(kf, qf1, (f32x4)0.f, 0, 0, 0);

            float p00 = exp2_raw(st0[0]);
            float p01 = exp2_raw(st0[1]);
            float p02 = exp2_raw(st0[2]);
            float p03 = exp2_raw(st0[3]);
            float p10 = exp2_raw(st1[0]);
            float p11 = exp2_raw(st1[1]);
            float p12 = exp2_raw(st1[2]);
            float p13 = exp2_raw(st1[3]);
            lacc0 += (p00 + p01) + (p02 + p03);
            lacc1 += (p10 + p11) + (p12 + p13);

            f16x4 pf0, pf1;
            pf0[0] = (_Float16)p00; pf0[1] = (_Float16)p01;
            pf0[2] = (_Float16)p02; pf0[3] = (_Float16)p03;
            pf1[0] = (_Float16)p10; pf1[1] = (_Float16)p11;
            pf1[2] = (_Float16)p12; pf1[3] = (_Float16)p13;

            oacc0 = __builtin_amdgcn_mfma_f32_16x16x16f16(pf0, vf, oacc0, 0, 0, 0);
            oacc1 = __builtin_amdgcn_mfma_f32_16x16x16f16(pf1, vf, oacc1, 0, 0, 0);
        }
    }

    lacc0 += __shfl_xor(lacc0, 16, 64);
    lacc0 += __shfl_xor(lacc0, 32, 64);
    lacc1 += __shfl_xor(lacc1, 16, 64);
    lacc1 += __shfl_xor(lacc1, 32, 64);

    #pragma unroll
    for (int r = 0; r < 4; ++r) {
        const float ls0 = __shfl(lacc0, quad * 4 + r, 64);
        const float ls1 = __shfl(lacc1, quad * 4 + r, 64);
        o[((size_t)b * Sq + q0 + quad * 4 + r) * Dq + h * DHq + m16]      = (_Float16)(oacc0[r] / ls0);
        o[((size_t)b * Sq + q0 + 16 + quad * 4 + r) * Dq + h * DHq + m16] = (_Float16)(oacc1[r] / ls1);
    }
}

// ---------------------------------------------------------------------------
extern "C" void kernel_launch(void* const* d_in, const int* in_sizes, int n_in,
                              void* d_out, int out_size, void* d_ws, size_t ws_size,
                              hipStream_t stream)
{
    const float* x_in  = (const float*)d_in[0];
    const float* Wq    = (const float*)d_in[1];
    const float* bq    = (const float*)d_in[2];
    const float* Wk    = (const float*)d_in[3];
    const float* bk    = (const float*)d_in[4];
    const float* Wv    = (const float*)d_in[5];
    const float* bv    = (const float*)d_in[6];
    const float* ln1_g = (const float*)d_in[7];
    const float* ln1_b = (const float*)d_in[8];
    const float* W1    = (const float*)d_in[9];
    const float* b1    = (const float*)d_in[10];
    const float* W2    = (const float*)d_in[11];
    const float* b2    = (const float*)d_in[12];
    const float* ln2_g = (const float*)d_in[13];
    const float* ln2_b = (const float*)d_in[14];
    const float* Wout  = (const float*)d_in[15];
    const float* bout  = (const float*)d_in[16];
    float* out = (float*)d_out;

    float* ws = (float*)d_ws;
    _Float16* qf16 = (_Float16*)ws;                         // [0, 0.5NX)
    _Float16* kf16 = (_Float16*)(ws + NX / 2);              // [0.5, 1NX)
    _Float16* vt16 = (_Float16*)(ws + NX);                  // [1, 1.5NX)
    float*    xb   = ws + 9 * NX / 2;                       // [4.5, 5.5NX)
    ushort*   xbf0 = (ushort*)(ws + 11 * NX / 2);           // [5.5, 6NX)
    ushort*   wbf  = (ushort*)(ws + 7 * NX);                // [7, ~7.26NX)
    _Float16* obuf = (_Float16*)(ws + 8 * NX);              // [8, 8.25NX) f16

    prep_kernel<<<dim3(10304), dim3(256), 0, stream>>>(Wq, Wk, Wv, W1, W2, x_in, wbf, xbf0);

    const dim3 blk(256);

    // layer-0 QKV (from x cast)
    {
        const ushort* wqt = wbf + (size_t)0 * 16384;
        const ushort* wkt = wbf + (size_t)3 * 16384;
        const ushort* wvt = wbf + (size_t)6 * 16384;
        gemm_qkv<<<dim3(256, 3), blk, 0, stream>>>(
            xbf0, wqt, wkt, wvt, bq, bk, bv, qf16, kf16, vt16);
    }

    const float* xcur = x_in;
    for (int l = 0; l < Lq; ++l) {
        const ushort* w1t = wbf + 147456 + (size_t)l * 65536;
        const ushort* w2t = wbf + 344064 + (size_t)l * 65536;
        const int next = (l < Lq - 1) ? 1 : 0;
        const int ln   = l + 1;
        const ushort* wqn = next ? (wbf + (size_t)(0 * 3 + ln) * 16384) : wbf;
        const ushort* wkn = next ? (wbf + (size_t)(1 * 3 + ln) * 16384) : wbf;
        const ushort* wvn = next ? (wbf + (size_t)(2 * 3 + ln) * 16384) : wbf;
        const float*  bqn = next ? (bq + ln * Dq) : bq;
        const float*  bkn = next ? (bk + ln * Dq) : bk;
        const float*  bvn = next ? (bv + ln * Dq) : bv;

        attn_mfma<<<dim3(Bq * Hq, 8), blk, 0, stream>>>(qf16, kf16, vt16, obuf);

        gemm_ffn_fused<<<dim3(512), blk, 0, stream>>>(
            obuf, xcur, ln1_g + l * Dq, ln1_b + l * Dq,
            w1t, b1 + l * DFFq, w2t, b2 + l * Dq,
            ln2_g + l * Dq, ln2_b + l * Dq,
            xb,
            wqn, wkn, wvn, bqn, bkn, bvn,
            qf16, kf16, vt16, next,
            Wout, bout, out, (l == Lq - 1) ? 1 : 0);

        xcur = xb;
    }
}